// Round 1
// baseline (62.499 us; speedup 1.0000x reference)
//
#include <hip/hip_runtime.h>
#include <hip/hip_bf16.h>

// kernel[i,j] = | prod_{k<16} cos((x[i,k]-y[j,k])/2) |   (f32 in, f32 out)
//
// r14: split into (1) qfact — one-shot factor-table generation (the old
// per-block staging computed every row's factors 32x redundantly; now 1x),
// and (2) qmain — LDS-free, barrier-free MFMA kernel. Tables are stored in
// fragment order so each wave's operand load is a single contiguous 1 KB
// burst: [rowblock=32 rows][granule g=q*2+kh (8)][row&31][16 B].
// Tables: 2048 vectors x 64 bf16 = 256 KB each -> L2-resident.
//
// MFMA math identical to r13 (verified, absmax 0.0039): per wire pair
// cos(a)cos(b) = 1/2[cos(Rm-Cm)+cos(Rp-Cp)] -> 4-term separable dot; quad =
// 16-term dot; out = |Q0 Q1 Q2 Q3| via 4x mfma_f32_32x32x16_bf16 (K=16 exact).
// A=row factors, B=col factors => D lane dim walks output columns (m74/m101).

constexpr int D = 16;

typedef short  bf16x8 __attribute__((ext_vector_type(8)));
typedef float  f32x16 __attribute__((ext_vector_type(16)));

// 64 rowblocks x 8 granules x 32 rows x 8 shorts = 128K shorts = 256 KB each.
__device__ __align__(16) unsigned short Atab[64 * 2048];
__device__ __align__(16) unsigned short Btab[64 * 2048];

static __device__ inline unsigned int pk2(float a, float b) {
    __hip_bfloat16 ha = __float2bfloat16(a);
    __hip_bfloat16 hb = __float2bfloat16(b);
    unsigned short ua, ub;
    __builtin_memcpy(&ua, &ha, 2);
    __builtin_memcpy(&ub, &hb, 2);
    return (unsigned int)ua | ((unsigned int)ub << 16);
}

// ---- Kernel 1: factor tables, 2 threads per vector (same math as r13 stage).
__global__ __launch_bounds__(256)
void qfact(const float* __restrict__ x, const float* __restrict__ y, int n) {
    const int tid  = blockIdx.x * 256 + threadIdx.x;
    const int u    = tid >> 1;          // vector index: 0..n-1 rows, n..n+m-1 cols
    const int half = tid & 1;
    const bool isrow = (u < n);
    const int  v   = isrow ? u : u - n;
    const float* src = (isrow ? x : y) + (size_t)v * D;
    unsigned short* tab = isrow ? Atab : Btab;
    const float scale = isrow ? 0.5f : 1.0f;   // 0.5*0.5 per row-pair -> 1/4 per quad

    float e[8];
    *(float4*)(e)     = *(const float4*)(src + 8 * half);
    *(float4*)(e + 4) = *(const float4*)(src + 8 * half + 4);

    float f[4][4];
#pragma unroll
    for (int pp = 0; pp < 4; ++pp) {
        const float a0 = e[2 * pp], a1 = e[2 * pp + 1];
        float sm, cm, sp, cp;
        __sincosf(0.5f * (a0 - a1), &sm, &cm);
        __sincosf(0.5f * (a0 + a1), &sp, &cp);
        f[pp][0] = scale * cm; f[pp][1] = scale * sm;
        f[pp][2] = scale * cp; f[pp][3] = scale * sp;
    }

    unsigned short* dst = tab + (size_t)(v >> 5) * 2048 + (size_t)(v & 31) * 8;
#pragma unroll
    for (int qq = 0; qq < 2; ++qq) {
        const int q = half * 2 + qq;
        const float* fa = f[2 * qq];
        const float* fb = f[2 * qq + 1];
        uint4 lo, hi;
        lo.x = pk2(fa[0] * fb[0], fa[0] * fb[1]);
        lo.y = pk2(fa[0] * fb[2], fa[0] * fb[3]);
        lo.z = pk2(fa[1] * fb[0], fa[1] * fb[1]);
        lo.w = pk2(fa[1] * fb[2], fa[1] * fb[3]);
        hi.x = pk2(fa[2] * fb[0], fa[2] * fb[1]);
        hi.y = pk2(fa[2] * fb[2], fa[2] * fb[3]);
        hi.z = pk2(fa[3] * fb[0], fa[3] * fb[1]);
        hi.w = pk2(fa[3] * fb[2], fa[3] * fb[3]);
        *(uint4*)(dst + (size_t)(q * 2 + 0) * 256) = lo;   // granule (q, kh=0): k0..7
        *(uint4*)(dst + (size_t)(q * 2 + 1) * 256) = hi;   // granule (q, kh=1): k8..15
    }
}

// ---- Kernel 2: no LDS, no barrier. Wave = one independent 32x32 tile.
__global__ __launch_bounds__(256)
void qmain(float* __restrict__ out, int m) {
    const int wave = threadIdx.x >> 6;
    const int lane = threadIdx.x & 63;
    const int l31  = lane & 31;
    const int kh   = lane >> 5;                 // k-half -> granule select
    const int rb   = blockIdx.x * 2 + (wave >> 1);   // 32-row block
    const int cb   = blockIdx.y * 2 + (wave & 1);    // 32-col block

    // Per q: lanes 0..31 read contiguous 512 B (granule q*2), lanes 32..63 the
    // adjacent 512 B (granule q*2+1) -> each load inst = one 1 KB burst.
    const unsigned short* abase = Atab + (size_t)rb * 2048 + (size_t)kh * 256 + (size_t)l31 * 8;
    const unsigned short* bbase = Btab + (size_t)cb * 2048 + (size_t)kh * 256 + (size_t)l31 * 8;

    bf16x8 a0 = *(const bf16x8*)(abase);
    bf16x8 b0 = *(const bf16x8*)(bbase);
    bf16x8 a1 = *(const bf16x8*)(abase + 512);
    bf16x8 b1 = *(const bf16x8*)(bbase + 512);
    bf16x8 a2 = *(const bf16x8*)(abase + 1024);
    bf16x8 b2 = *(const bf16x8*)(bbase + 1024);
    bf16x8 a3 = *(const bf16x8*)(abase + 1536);
    bf16x8 b3 = *(const bf16x8*)(bbase + 1536);

    const f32x16 zc = {0.f};
    f32x16 q0 = __builtin_amdgcn_mfma_f32_32x32x16_bf16(a0, b0, zc, 0, 0, 0);
    f32x16 q1 = __builtin_amdgcn_mfma_f32_32x32x16_bf16(a1, b1, zc, 0, 0, 0);
    f32x16 q2 = __builtin_amdgcn_mfma_f32_32x32x16_bf16(a2, b2, zc, 0, 0, 0);
    f32x16 q3 = __builtin_amdgcn_mfma_f32_32x32x16_bf16(a3, b3, zc, 0, 0, 0);
    const f32x16 prod = (q0 * q1) * (q2 * q3);

    // D reg r -> row = 32*rb + (r&3) + 8*(r>>2) + 4*kh; col = 32*cb + l31.
    // Lanes walk contiguous cols -> each store covers 2 x 128 B full lines.
    const int ocol = cb * 32 + l31;
    float* base = out + (size_t)(rb * 32 + 4 * kh) * m + ocol;
#pragma unroll
    for (int r = 0; r < 16; ++r) {
        const int row_off = (r & 3) + 8 * (r >> 2);
        __builtin_nontemporal_store(fabsf(prod[r]), base + (size_t)row_off * m);
    }
}

extern "C" void kernel_launch(void* const* d_in, const int* in_sizes, int n_in,
                              void* d_out, int out_size, void* d_ws, size_t ws_size,
                              hipStream_t stream) {
    const float* x = (const float*)d_in[0];
    const float* y = (const float*)d_in[1];
    float* out = (float*)d_out;
    const int n = in_sizes[0] / D;   // 2048
    const int m = in_sizes[1] / D;   // 2048

    const int nvec = n + m;                       // 4096 vectors
    qfact<<<dim3((nvec * 2) / 256), 256, 0, stream>>>(x, y, n);

    dim3 grid(n / 64, m / 64);                    // 32 x 32 blocks, 4 waves each
    qmain<<<grid, 256, 0, stream>>>(out, m);
}